// Round 2
// baseline (161.254 us; speedup 1.0000x reference)
//
#include <hip/hip_runtime.h>

// LBP 'var' texture loss, MI355X. Shapes fixed by reference: [16,3,512,512] f32.
#define IMG_H 512
#define IMG_W 512
#define TILE_X 64
#define TILE_Y 16
#define LDS_H  20   // TILE_Y + 2*halo
#define LDS_COLS 68 // TILE_X + 2*halo
#define LDS_W  72   // padded stride, 16B-aligned rows
#define NBLOCKS ((IMG_W / TILE_X) * (IMG_H / TILE_Y) * 48)  // 8*32*48 = 12288

// Circle offsets, exactly matching np.round(±2*sin/cos(2*pi*i/16), 8)
constexpr double RPV[16] = {
   0.0,        -0.76536686, -1.41421356, -1.84775907,
  -2.0,        -1.84775907, -1.41421356, -0.76536686,
   0.0,         0.76536686,  1.41421356,  1.84775907,
   2.0,         1.84775907,  1.41421356,  0.76536686
};
constexpr double CPV[16] = {
   2.0,         1.84775907,  1.41421356,  0.76536686,
   0.0,        -0.76536686, -1.41421356, -1.84775907,
  -2.0,        -1.84775907, -1.41421356, -0.76536686,
   0.0,         0.76536686,  1.41421356,  1.84775907
};

constexpr int cfloor(double x) {
  int i = (int)x;
  return (x < (double)i) ? i - 1 : i;
}

// One circle point: bilinear sample from the 5x8 register window, accumulate
// s1/s2 in the same order as the reference (taps: 00,01,10,11; skip w<=1e-12).
template<int I>
__device__ __forceinline__ void lbp_point(const float (&w)[5][8], int px,
                                          float& s1, float& s2) {
  constexpr double rp = RPV[I], cp = CPV[I];
  constexpr int fr = cfloor(rp), fc = cfloor(cp);
  constexpr double tr = rp - (double)fr, tc = cp - (double)fc;
  constexpr double w00 = (1.0 - tr) * (1.0 - tc);
  constexpr double w01 = (1.0 - tr) * tc;
  constexpr double w10 = tr * (1.0 - tc);
  constexpr double w11 = tr * tc;
  float v = 0.0f;
  if constexpr (w00 > 1e-12) v += (float)w00 * w[fr + 2][px + fc + 2];
  if constexpr (w01 > 1e-12) v += (float)w01 * w[fr + 2][px + fc + 3];
  if constexpr (w10 > 1e-12) v += (float)w10 * w[fr + 3][px + fc + 2];
  if constexpr (w11 > 1e-12) v += (float)w11 * w[fr + 3][px + fc + 3];
  s1 += v;
  s2 += v * v;
}

__device__ __forceinline__ void lbp_all16(const float (&w)[5][8], int px,
                                          float& s1, float& s2) {
  lbp_point<0>(w, px, s1, s2);  lbp_point<1>(w, px, s1, s2);
  lbp_point<2>(w, px, s1, s2);  lbp_point<3>(w, px, s1, s2);
  lbp_point<4>(w, px, s1, s2);  lbp_point<5>(w, px, s1, s2);
  lbp_point<6>(w, px, s1, s2);  lbp_point<7>(w, px, s1, s2);
  lbp_point<8>(w, px, s1, s2);  lbp_point<9>(w, px, s1, s2);
  lbp_point<10>(w, px, s1, s2); lbp_point<11>(w, px, s1, s2);
  lbp_point<12>(w, px, s1, s2); lbp_point<13>(w, px, s1, s2);
  lbp_point<14>(w, px, s1, s2); lbp_point<15>(w, px, s1, s2);
}

__global__ __launch_bounds__(256)
void lbp_loss_kernel(const float* __restrict__ A, const float* __restrict__ B,
                     double* __restrict__ part) {
  __shared__ __align__(16) float tile[2][LDS_H][LDS_W];
  __shared__ double bsum[4];

  const int tid = threadIdx.x;
  const int bx = blockIdx.x, by = blockIdx.y, z = blockIdx.z;
  const int row0 = by * TILE_Y - 2;
  const int col0 = bx * TILE_X - 2;
  const size_t ibase = (size_t)z * (IMG_H * IMG_W);

  // Stage both image tiles (zero-padded). float2 pairs are even-aligned so a
  // pair is either fully inside [0,512) or fully outside -> single check.
  const int PAIRS = LDS_COLS / 2;             // 34
  const int PER_IMG = LDS_H * PAIRS;          // 680
  for (int idx = tid; idx < 2 * PER_IMG; idx += 256) {
    const int im = idx >= PER_IMG;
    const int k = im ? idx - PER_IMG : idx;
    const int r = k / PAIRS;
    const int pc = k - r * PAIRS;
    const int gr = row0 + r;
    const int gc = col0 + pc * 2;
    float2 v = make_float2(0.0f, 0.0f);
    if ((unsigned)gr < (unsigned)IMG_H && (unsigned)gc < (unsigned)(IMG_W - 1)) {
      const float* __restrict__ src = im ? B : A;
      v = *(const float2*)&src[ibase + (size_t)gr * IMG_W + gc];
    }
    tile[im][r][pc * 2]     = v.x;
    tile[im][r][pc * 2 + 1] = v.y;
  }
  __syncthreads();

  const int tx = tid & 15;   // 16 threads across, 4 px each -> 64 cols
  const int ty = tid >> 4;   // 16 rows

  float var2[2][4];
  #pragma unroll
  for (int im = 0; im < 2; ++im) {
    // 5x8 register window covers taps dr,dc in [-2,2] for 4 consecutive px.
    float w[5][8];
    #pragma unroll
    for (int r = 0; r < 5; ++r) {
      float4 a = *(const float4*)&tile[im][ty + r][tx * 4];
      float4 b = *(const float4*)&tile[im][ty + r][tx * 4 + 4];
      w[r][0] = a.x; w[r][1] = a.y; w[r][2] = a.z; w[r][3] = a.w;
      w[r][4] = b.x; w[r][5] = b.y; w[r][6] = b.z; w[r][7] = b.w;
    }
    #pragma unroll
    for (int px = 0; px < 4; ++px) {
      float s1 = 0.0f, s2 = 0.0f;
      lbp_all16(w, px, s1, s2);
      float mean = s1 * 0.0625f;
      var2[im][px] = s2 * 0.0625f - mean * mean;
    }
  }

  float local = 0.0f;
  #pragma unroll
  for (int px = 0; px < 4; ++px) {
    float d = var2[0][px] - var2[1][px];
    local += d * d;
  }

  // wave64 shuffle reduce -> 4 wave sums -> one f64 partial per block.
  #pragma unroll
  for (int off = 32; off > 0; off >>= 1)
    local += __shfl_down(local, off, 64);
  if ((tid & 63) == 0) bsum[tid >> 6] = (double)local;
  __syncthreads();
  if (tid == 0) {
    const int bflat = bx + gridDim.x * (by + gridDim.y * z);
    part[bflat] = bsum[0] + bsum[1] + bsum[2] + bsum[3];
  }
}

__global__ __launch_bounds__(1024)
void reduce_kernel(const double* __restrict__ part, int n,
                   float* __restrict__ out, double inv_n) {
  __shared__ double sm[16];
  double s = 0.0;
  for (int i = threadIdx.x; i < n; i += 1024) s += part[i];
  #pragma unroll
  for (int off = 32; off > 0; off >>= 1)
    s += __shfl_down(s, off, 64);
  if ((threadIdx.x & 63) == 0) sm[threadIdx.x >> 6] = s;
  __syncthreads();
  if (threadIdx.x < 16) {
    double t = sm[threadIdx.x];
    #pragma unroll
    for (int off = 8; off > 0; off >>= 1)
      t += __shfl_down(t, off, 64);
    if (threadIdx.x == 0) out[0] = (float)(t * inv_n);
  }
}

extern "C" void kernel_launch(void* const* d_in, const int* in_sizes, int n_in,
                              void* d_out, int out_size, void* d_ws, size_t ws_size,
                              hipStream_t stream) {
  const float* A = (const float*)d_in[0];   // output
  const float* B = (const float*)d_in[1];   // target
  float* out = (float*)d_out;
  double* part = (double*)d_ws;             // 12288 doubles = 98 KB scratch

  const int total = in_sizes[0];                 // 16*3*512*512 = 12,582,912
  const int BC = total / (IMG_H * IMG_W);        // 48
  dim3 grid(IMG_W / TILE_X, IMG_H / TILE_Y, BC); // (8, 32, 48)
  lbp_loss_kernel<<<grid, 256, 0, stream>>>(A, B, part);

  const int nblocks = grid.x * grid.y * grid.z;
  reduce_kernel<<<1, 1024, 0, stream>>>(part, nblocks, out, 1.0 / (double)total);
}

// Round 3
// 143.313 us; speedup vs baseline: 1.1252x; 1.1252x over previous
//
#include <hip/hip_runtime.h>

// LBP 'var' texture loss, MI355X. Shapes fixed by reference: [16,3,512,512] f32.
// Key idea: images A (output) and B (target) run the IDENTICAL 52-tap stencil,
// so interleave them as float2 {A,B} pairs and use CDNA4 full-rate packed fp32
// (v_pk_fma_f32) — one packed instruction does both images.

typedef float f2 __attribute__((ext_vector_type(2)));

#define IMG_H 512
#define IMG_W 512
#define TILE_X 64
#define TILE_Y 16
#define LDS_H  20   // TILE_Y + 2*2 halo rows
#define LDS_CP 72   // pair-cols covered per row: [bx*64-4, bx*64+68)
#define LDS_SP 74   // padded pair stride (592 B, 16B-multiple -> b128-friendly)

// Circle offsets, exactly matching np.round(±2*sin/cos(2*pi*i/16), 8)
constexpr double RPV[16] = {
   0.0,        -0.76536686, -1.41421356, -1.84775907,
  -2.0,        -1.84775907, -1.41421356, -0.76536686,
   0.0,         0.76536686,  1.41421356,  1.84775907,
   2.0,         1.84775907,  1.41421356,  0.76536686
};
constexpr double CPV[16] = {
   2.0,         1.84775907,  1.41421356,  0.76536686,
   0.0,        -0.76536686, -1.41421356, -1.84775907,
  -2.0,        -1.84775907, -1.41421356, -0.76536686,
   0.0,         0.76536686,  1.41421356,  1.84775907
};

constexpr int cfloor(double x) {
  int i = (int)x;
  return (x < (double)i) ? i - 1 : i;
}

__device__ __forceinline__ f2 splat(float x) { f2 r; r.x = x; r.y = x; return r; }

// One circle point, packed over {A,B}. Tap order 00,01,10,11 with w<=1e-12
// skipped, mirroring the reference loop exactly.
template<int I>
__device__ __forceinline__ void lbp_point(const f2 (&w)[5][8], int px,
                                          f2& s1, f2& s2) {
  constexpr double rp = RPV[I], cp = CPV[I];
  constexpr int fr = cfloor(rp), fc = cfloor(cp);
  constexpr double tr = rp - (double)fr, tc = cp - (double)fc;
  constexpr double W00 = (1.0 - tr) * (1.0 - tc);
  constexpr double W01 = (1.0 - tr) * tc;
  constexpr double W10 = tr * (1.0 - tc);
  constexpr double W11 = tr * tc;
  f2 v = splat(0.0f);
  if constexpr (W00 > 1e-12)
    v = __builtin_elementwise_fma(splat((float)W00), w[fr + 2][px + fc + 2], v);
  if constexpr (W01 > 1e-12)
    v = __builtin_elementwise_fma(splat((float)W01), w[fr + 2][px + fc + 3], v);
  if constexpr (W10 > 1e-12)
    v = __builtin_elementwise_fma(splat((float)W10), w[fr + 3][px + fc + 2], v);
  if constexpr (W11 > 1e-12)
    v = __builtin_elementwise_fma(splat((float)W11), w[fr + 3][px + fc + 3], v);
  s1 = s1 + v;
  s2 = __builtin_elementwise_fma(v, v, s2);
}

__device__ __forceinline__ void lbp_all16(const f2 (&w)[5][8], int px,
                                          f2& s1, f2& s2) {
  lbp_point<0>(w, px, s1, s2);  lbp_point<1>(w, px, s1, s2);
  lbp_point<2>(w, px, s1, s2);  lbp_point<3>(w, px, s1, s2);
  lbp_point<4>(w, px, s1, s2);  lbp_point<5>(w, px, s1, s2);
  lbp_point<6>(w, px, s1, s2);  lbp_point<7>(w, px, s1, s2);
  lbp_point<8>(w, px, s1, s2);  lbp_point<9>(w, px, s1, s2);
  lbp_point<10>(w, px, s1, s2); lbp_point<11>(w, px, s1, s2);
  lbp_point<12>(w, px, s1, s2); lbp_point<13>(w, px, s1, s2);
  lbp_point<14>(w, px, s1, s2); lbp_point<15>(w, px, s1, s2);
}

__global__ __launch_bounds__(256)
void lbp_loss_kernel(const float* __restrict__ A, const float* __restrict__ B,
                     double* __restrict__ part) {
  __shared__ __align__(16) f2 tile[LDS_H][LDS_SP];
  __shared__ double bsum[4];

  const int tid = threadIdx.x;
  const int bx = blockIdx.x, by = blockIdx.y, z = blockIdx.z;
  const int row0 = by * TILE_Y - 2;
  const int col0 = bx * TILE_X - 4;   // aligned-float4 halo start
  const size_t ibase = (size_t)z * (IMG_H * IMG_W);

  // Stage interleaved {A,B} pairs. 18 aligned float4-quads per row x 20 rows.
  // col0 is a multiple of 4 minus 0 (bx*64-4), so every global float4 load is
  // 16B-aligned; a quad is fully inside [0,512) or fully outside -> one check.
  const int QUADS = LDS_CP / 4;            // 18
  const int SLOTS = LDS_H * QUADS;         // 360 (<512 -> at most 2 iters)
  for (int idx = tid; idx < SLOTS; idx += 256) {
    const int r = idx / QUADS;
    const int q = idx - r * QUADS;
    const int gr = row0 + r;
    const int gc = col0 + q * 4;
    float4 a = make_float4(0.f, 0.f, 0.f, 0.f);
    float4 b = make_float4(0.f, 0.f, 0.f, 0.f);
    if ((unsigned)gr < (unsigned)IMG_H && (unsigned)gc < (unsigned)IMG_W) {
      const size_t off = ibase + (size_t)gr * IMG_W + gc;
      a = *(const float4*)&A[off];
      b = *(const float4*)&B[off];
    }
    f2* dst = &tile[r][q * 4];
    dst[0] = f2{a.x, b.x};
    dst[1] = f2{a.y, b.y};
    dst[2] = f2{a.z, b.z};
    dst[3] = f2{a.w, b.w};
  }
  __syncthreads();

  const int tx = tid & 15;   // 16 threads across, 4 px each -> 64 cols
  const int ty = tid >> 4;   // 16 rows

  // 5x8 pair window: rows ty..ty+4, pair-cols tx*4+2 .. tx*4+9.
  // Byte offset (74*r + 4*tx + 2)*8 = 592r + 32tx + 16 -> 16B aligned: b128 x4.
  f2 w[5][8];
  #pragma unroll
  for (int r = 0; r < 5; ++r) {
    const f2* lp = &tile[ty + r][tx * 4 + 2];
    float4 q0 = *(const float4*)(lp + 0);
    float4 q1 = *(const float4*)(lp + 2);
    float4 q2 = *(const float4*)(lp + 4);
    float4 q3 = *(const float4*)(lp + 6);
    w[r][0] = f2{q0.x, q0.y}; w[r][1] = f2{q0.z, q0.w};
    w[r][2] = f2{q1.x, q1.y}; w[r][3] = f2{q1.z, q1.w};
    w[r][4] = f2{q2.x, q2.y}; w[r][5] = f2{q2.z, q2.w};
    w[r][6] = f2{q3.x, q3.y}; w[r][7] = f2{q3.z, q3.w};
  }

  float local = 0.0f;
  #pragma unroll
  for (int px = 0; px < 4; ++px) {
    f2 s1 = splat(0.0f), s2 = splat(0.0f);
    lbp_all16(w, px, s1, s2);
    f2 mean = s1 * 0.0625f;
    f2 var  = __builtin_elementwise_fma(-mean, mean, s2 * 0.0625f);
    const float d = var.x - var.y;
    local = fmaf(d, d, local);
  }

  // wave64 shuffle reduce -> 4 wave sums -> one f64 partial per block.
  #pragma unroll
  for (int off = 32; off > 0; off >>= 1)
    local += __shfl_down(local, off, 64);
  if ((tid & 63) == 0) bsum[tid >> 6] = (double)local;
  __syncthreads();
  if (tid == 0) {
    const int bflat = bx + gridDim.x * (by + gridDim.y * z);
    part[bflat] = bsum[0] + bsum[1] + bsum[2] + bsum[3];
  }
}

__global__ __launch_bounds__(1024)
void reduce_kernel(const double* __restrict__ part, int n,
                   float* __restrict__ out, double inv_n) {
  __shared__ double sm[16];
  double s = 0.0;
  for (int i = threadIdx.x; i < n; i += 1024) s += part[i];
  #pragma unroll
  for (int off = 32; off > 0; off >>= 1)
    s += __shfl_down(s, off, 64);
  if ((threadIdx.x & 63) == 0) sm[threadIdx.x >> 6] = s;
  __syncthreads();
  if (threadIdx.x < 16) {
    double t = sm[threadIdx.x];
    #pragma unroll
    for (int off = 8; off > 0; off >>= 1)
      t += __shfl_down(t, off, 64);
    if (threadIdx.x == 0) out[0] = (float)(t * inv_n);
  }
}

extern "C" void kernel_launch(void* const* d_in, const int* in_sizes, int n_in,
                              void* d_out, int out_size, void* d_ws, size_t ws_size,
                              hipStream_t stream) {
  const float* A = (const float*)d_in[0];   // output
  const float* B = (const float*)d_in[1];   // target
  float* out = (float*)d_out;
  double* part = (double*)d_ws;             // 12288 doubles = 98 KB scratch

  const int total = in_sizes[0];                 // 16*3*512*512 = 12,582,912
  const int BC = total / (IMG_H * IMG_W);        // 48
  dim3 grid(IMG_W / TILE_X, IMG_H / TILE_Y, BC); // (8, 32, 48)
  lbp_loss_kernel<<<grid, 256, 0, stream>>>(A, B, part);

  const int nblocks = grid.x * grid.y * grid.z;
  reduce_kernel<<<1, 1024, 0, stream>>>(part, nblocks, out, 1.0 / (double)total);
}